// Round 10
// baseline (33.739 us; speedup 1.0000x reference)
//
#include <hip/hip_runtime.h>

#define BS 128
#define KJ 17
#define HW 4096
#define CHUNKS 16
#define NBLK1 (BS * CHUNKS)      // 2048 blocks; block = 4 teams x 64 thr
#define NBK (BS * KJ)            // 2176
#define KSEL 1088                // int(2176 * (1 - 0.5))

// ws float offsets (folded layout: k1 accumulates directly via atomics)
#define LW_OFF 0
#define SA_OFF NBK
#define SB_OFF (2 * NBK)
#define THR_OFF (3 * NBK)            // +2 floats
#define WS_ZERO_BYTES (3 * NBK * 4)  // LW/SA/SB must start at 0 each launch

typedef float v4f __attribute__((ext_vector_type(4)));

// Nontemporal float4 load: streams past L1 (nt flag). The 51 per-thread
// streams sit at 16KB stride -> alias the same L1 sets; bypassing L1
// removes the set-conflict serialization (data is touched exactly once).
__device__ __forceinline__ float4 ntload4(const float* p) {
    const v4f v = __builtin_nontemporal_load((const v4f*)p);
    return make_float4(v.x, v.y, v.z, v.w);
}

template<int K0, int NK>
__device__ __forceinline__ void team_pass1(const float* __restrict__ pb,
                                           const float* __restrict__ t0b,
                                           const float* __restrict__ t1b,
                                           int ti, float (*lb)[68],
                                           float4* pv, float4* tv,
                                           float4& spP, float4& spT) {
    float4 vb[NK];
#pragma unroll
    for (int j = 0; j < NK; ++j) pv[j] = ntload4(pb + (K0 + j) * HW);
#pragma unroll
    for (int j = 0; j < NK; ++j) tv[j] = ntload4(t0b + (K0 + j) * HW);
#pragma unroll
    for (int j = 0; j < NK; ++j) vb[j] = ntload4(t1b + (K0 + j) * HW);
    spP = make_float4(0.f, 0.f, 0.f, 0.f);
    spT = make_float4(0.f, 0.f, 0.f, 0.f);
#pragma unroll
    for (int j = 0; j < NK; ++j) {
        tv[j].x = 0.5f * (tv[j].x + vb[j].x);
        tv[j].y = 0.5f * (tv[j].y + vb[j].y);
        tv[j].z = 0.5f * (tv[j].z + vb[j].z);
        tv[j].w = 0.5f * (tv[j].w + vb[j].w);
        const float dx = pv[j].x - tv[j].x, dy = pv[j].y - tv[j].y;
        const float dz = pv[j].z - tv[j].z, dw = pv[j].w - tv[j].w;
        lb[K0 + j][ti] = dx * dx + dy * dy + dz * dz + dw * dw;
        spP.x += __expf(pv[j].x); spP.y += __expf(pv[j].y);
        spP.z += __expf(pv[j].z); spP.w += __expf(pv[j].w);
        spT.x += __expf(tv[j].x); spT.y += __expf(tv[j].y);
        spT.z += __expf(tv[j].z); spT.w += __expf(tv[j].w);
    }
}

template<int K0, int NK>
__device__ __forceinline__ void score_write(float (*lb)[68], int ti,
                                            const float4* v, float4 inv) {
#pragma unroll
    for (int j = 0; j < NK; ++j) {
        const float m = fmaxf(fmaxf(__expf(v[j].x) * inv.x, __expf(v[j].y) * inv.y),
                              fmaxf(__expf(v[j].z) * inv.z, __expf(v[j].w) * inv.w));
        lb[K0 + j][ti] = m;
    }
}

// ---------------- K1: nt float4 4-team split-k + atomic fold ----------
// Same streaming structure as R7/R9; the per-(b,chunk,k) partials are now
// folded directly into per-(b,k) slots: atomicAdd for the (pre-scaled)
// loss sum, atomicMax on float bits for score maxima (exact: positive
// floats order as their bits, max is order-independent).
__global__ __launch_bounds__(256, 4) void k1_reduce(const float* __restrict__ preds,
                                                    const float* __restrict__ targets,
                                                    const float* __restrict__ sw,
                                                    float* __restrict__ ws) {
    __shared__ float lb[KJ][68];
    __shared__ float4 sP[4][64];
    __shared__ float4 sT[4][64];
    __shared__ float buf2[KJ][4];

    const int bid = blockIdx.x;
    const int b = bid >> 4;
    const int c = bid & 15;
    const int tid = threadIdx.x;
    const int tm = tid >> 6;
    const int ti = tid & 63;
    const int s0 = (c << 8) | (ti << 2);

    const float* pb  = preds   + (size_t)b * KJ * HW + s0;
    const float* t0b = targets + (size_t)b * KJ * HW + s0;
    const float* t1b = targets + (size_t)(BS + b) * KJ * HW + s0;

    float4 pv[5], tv[5], spP, spT;
    if      (tm == 0) team_pass1<0, 4>(pb, t0b, t1b, ti, lb, pv, tv, spP, spT);
    else if (tm == 1) team_pass1<4, 4>(pb, t0b, t1b, ti, lb, pv, tv, spP, spT);
    else if (tm == 2) team_pass1<8, 4>(pb, t0b, t1b, ti, lb, pv, tv, spP, spT);
    else              team_pass1<12, 5>(pb, t0b, t1b, ti, lb, pv, tv, spP, spT);
    sP[tm][ti] = spP;
    sT[tm][ti] = spT;
    __syncthreads();

    float4 invP, invT;
    {
        const float4 a0 = sP[0][ti], a1 = sP[1][ti], a2 = sP[2][ti], a3 = sP[3][ti];
        invP.x = 1.0f / (a0.x + a1.x + a2.x + a3.x);
        invP.y = 1.0f / (a0.y + a1.y + a2.y + a3.y);
        invP.z = 1.0f / (a0.z + a1.z + a2.z + a3.z);
        invP.w = 1.0f / (a0.w + a1.w + a2.w + a3.w);
        const float4 b0 = sT[0][ti], b1 = sT[1][ti], b2 = sT[2][ti], b3 = sT[3][ti];
        invT.x = 1.0f / (b0.x + b1.x + b2.x + b3.x);
        invT.y = 1.0f / (b0.y + b1.y + b2.y + b3.y);
        invT.z = 1.0f / (b0.z + b1.z + b2.z + b3.z);
        invT.w = 1.0f / (b0.w + b1.w + b2.w + b3.w);
    }

    if (tid < KJ * 4) {
        const int k = tid >> 2, seg = tid & 3;
        float r = 0.f;
#pragma unroll
        for (int i = 0; i < 16; ++i) {
            const int idx = (i + seg * 4) & 15;
            r += lb[k][(seg << 4) + idx];
        }
        buf2[k][seg] = r;
    }
    __syncthreads();

    if (tid < KJ) {
        const float r = buf2[tid][0] + buf2[tid][1] + buf2[tid][2] + buf2[tid][3];
        atomicAdd(&ws[LW_OFF + b * KJ + tid], r * (1.0f / HW) * sw[b]);
    }
    if      (tm == 0) score_write<0, 4>(lb, ti, pv, invP);
    else if (tm == 1) score_write<4, 4>(lb, ti, pv, invP);
    else if (tm == 2) score_write<8, 4>(lb, ti, pv, invP);
    else              score_write<12, 5>(lb, ti, pv, invP);
    __syncthreads();

    if (tid < KJ * 4) {
        const int k = tid >> 2, seg = tid & 3;
        float r = 0.f;
#pragma unroll
        for (int i = 0; i < 16; ++i) {
            const int idx = (i + seg * 4) & 15;
            r = fmaxf(r, lb[k][(seg << 4) + idx]);
        }
        buf2[k][seg] = r;
    }
    __syncthreads();

    if (tid < KJ) {
        const float r = fmaxf(fmaxf(buf2[tid][0], buf2[tid][1]),
                              fmaxf(buf2[tid][2], buf2[tid][3]));
        atomicMax((unsigned int*)&ws[SA_OFF + b * KJ + tid], __float_as_uint(r));
    }
    if      (tm == 0) score_write<0, 4>(lb, ti, tv, invT);
    else if (tm == 1) score_write<4, 4>(lb, ti, tv, invT);
    else if (tm == 2) score_write<8, 4>(lb, ti, tv, invT);
    else              score_write<12, 5>(lb, ti, tv, invT);
    __syncthreads();

    if (tid < KJ * 4) {
        const int k = tid >> 2, seg = tid & 3;
        float r = 0.f;
#pragma unroll
        for (int i = 0; i < 16; ++i) {
            const int idx = (i + seg * 4) & 15;
            r = fmaxf(r, lb[k][(seg << 4) + idx]);
        }
        buf2[k][seg] = r;
    }
    __syncthreads();

    if (tid < KJ) {
        const float r = fmaxf(fmaxf(buf2[tid][0], buf2[tid][1]),
                              fmaxf(buf2[tid][2], buf2[tid][3]));
        atomicMax((unsigned int*)&ws[SB_OFF + b * KJ + tid], __float_as_uint(r));
    }
}

// ---------------- K3: order statistic (folded offsets) ----------------
__global__ __launch_bounds__(256) void k3_select(float* __restrict__ ws) {
    const int w = blockIdx.x * 4 + (threadIdx.x >> 6);  // 0..4351
    const int lane = threadIdx.x & 63;
    const int arr = (w >= NBK) ? 1 : 0;
    const int cand = w - arr * NBK;
    const float* sc = ws + (arr ? SB_OFF : SA_OFF);
    const float e = sc[cand];
    int clt = 0, cle = 0;
    for (int j = lane; j < NBK; j += 64) {
        float x = sc[j];
        clt += (x < e) ? 1 : 0;
        cle += (x <= e) ? 1 : 0;
    }
#pragma unroll
    for (int off = 32; off > 0; off >>= 1) {
        clt += __shfl_xor(clt, off, 64);
        cle += __shfl_xor(cle, off, 64);
    }
    if (lane == 0 && clt <= KSEL && KSEL < cle) {
        ws[THR_OFF + arr] = e;  // unique value; benign same-value race
    }
}

// ---------------- K4: finalize, fully parallel (512 thr) ----------------
__global__ __launch_bounds__(512) void k4_final(const float* __restrict__ ws,
                                                const float* __restrict__ sw,
                                                float* __restrict__ out) {
    const int tid = threadIdx.x;
    const int lane = tid & 63, wid = tid >> 6;
    const float thrA = ws[THR_OFF + 0];
    const float thrB = ws[THR_OFF + 1];

    float comb = 0.f, np = 0.f, ns = 0.f;
    for (int e = tid; e < NBK; e += 512) {
        const float L  = ws[LW_OFF + e];
        const float s1 = ws[SA_OFF + e];
        const float s2 = ws[SB_OFF + e];
        const float m = (s1 >= thrA && s2 >= thrB) ? 1.f : 0.f;
        comb += L * m;
        np += (L > 0.f) ? 1.f : 0.f;
        ns += m;
    }
#pragma unroll
    for (int off = 32; off > 0; off >>= 1) {
        comb += __shfl_xor(comb, off, 64);
        np   += __shfl_xor(np, off, 64);
        ns   += __shfl_xor(ns, off, 64);
    }
    __shared__ float wr[8][3];
    if (lane == 0) { wr[wid][0] = comb; wr[wid][1] = np; wr[wid][2] = ns; }
    __syncthreads();
    if (tid == 0) {
        float C = 0.f, NP = 0.f, NS = 0.f;
#pragma unroll
        for (int i = 0; i < 8; ++i) { C += wr[i][0]; NP += wr[i][1]; NS += wr[i][2]; }
        out[0] = C;
        out[1] = NP;
        out[2] = NS;
        out[20] = thrA;
        out[21] = thrB;
    }

    // joint_score_mean: 16 lanes per k, 8 b's per lane, 16-wide shfl reduce
    if (tid < KJ * 16) {
        const int k = tid >> 4, l = tid & 15;
        float a1 = 0.f, a2 = 0.f, cnt = 0.f;
#pragma unroll
        for (int i = 0; i < 8; ++i) {
            const int b = l + i * 16;
            const float wf = (sw[b] > 0.f) ? 1.f : 0.f;
            cnt += wf;
            a1 += ws[SA_OFF + b * KJ + k] * wf;
            a2 += ws[SB_OFF + b * KJ + k] * wf;
        }
#pragma unroll
        for (int off = 1; off < 16; off <<= 1) {
            a1  += __shfl_xor(a1, off, 16);
            a2  += __shfl_xor(a2, off, 16);
            cnt += __shfl_xor(cnt, off, 16);
        }
        if (l == 0) out[3 + k] = 0.5f * (a1 + a2) / cnt;
    }
}

extern "C" void kernel_launch(void* const* d_in, const int* in_sizes, int n_in,
                              void* d_out, int out_size, void* d_ws, size_t ws_size,
                              hipStream_t stream) {
    const float* preds   = (const float*)d_in[0];
    const float* targets = (const float*)d_in[1];
    const float* sw      = (const float*)d_in[2];
    float* out = (float*)d_out;
    float* ws  = (float*)d_ws;

    // LW/SA/SB accumulators must start at zero every call (harness does not
    // re-poison ws between replays). 26 KB memset: graph-capturable, ~0 cost.
    hipMemsetAsync(ws, 0, WS_ZERO_BYTES, stream);
    hipLaunchKernelGGL(k1_reduce, dim3(NBLK1), dim3(256), 0, stream, preds, targets, sw, ws);
    hipLaunchKernelGGL(k3_select, dim3((2 * NBK) / 4), dim3(256), 0, stream, ws);
    hipLaunchKernelGGL(k4_final, dim3(1), dim3(512), 0, stream, ws, sw, out);
}

// Round 11
// 32.945 us; speedup vs baseline: 1.0241x; 1.0241x over previous
//
#include <hip/hip_runtime.h>

#define BS 128
#define KJ 17
#define HW 4096
#define CHUNKS 16
#define NBLK1 (BS * CHUNKS)      // 2048 blocks; block = 4 teams x 64 thr
#define NBK (BS * KJ)            // 2176
#define KSEL 1088                // int(2176 * (1 - 0.5))

// ws float offsets
#define PL_OFF 0
#define S1_OFF (NBLK1 * KJ)
#define S2_OFF (2 * NBLK1 * KJ)
#define LW_OFF (3 * NBLK1 * KJ)
#define SA_OFF (LW_OFF + NBK)
#define SB_OFF (SA_OFF + NBK)
#define THR_OFF (SB_OFF + NBK)       // +2 floats

typedef float v4f __attribute__((ext_vector_type(4)));

// Nontemporal float4 load: streams past L1 (nt flag). The 51 per-thread
// streams sit at 16KB stride -> alias the same L1 sets; bypassing L1
// removes the set-conflict serialization (data is touched exactly once).
__device__ __forceinline__ float4 ntload4(const float* p) {
    const v4f v = __builtin_nontemporal_load((const v4f*)p);
    return make_float4(v.x, v.y, v.z, v.w);
}

template<int K0, int NK>
__device__ __forceinline__ void team_pass1(const float* __restrict__ pb,
                                           const float* __restrict__ t0b,
                                           const float* __restrict__ t1b,
                                           int ti, float (*lb)[68],
                                           float4* pv, float4* tv,
                                           float4& spP, float4& spT) {
    float4 vb[NK];
#pragma unroll
    for (int j = 0; j < NK; ++j) pv[j] = ntload4(pb + (K0 + j) * HW);
#pragma unroll
    for (int j = 0; j < NK; ++j) tv[j] = ntload4(t0b + (K0 + j) * HW);
#pragma unroll
    for (int j = 0; j < NK; ++j) vb[j] = ntload4(t1b + (K0 + j) * HW);
    spP = make_float4(0.f, 0.f, 0.f, 0.f);
    spT = make_float4(0.f, 0.f, 0.f, 0.f);
#pragma unroll
    for (int j = 0; j < NK; ++j) {
        tv[j].x = 0.5f * (tv[j].x + vb[j].x);
        tv[j].y = 0.5f * (tv[j].y + vb[j].y);
        tv[j].z = 0.5f * (tv[j].z + vb[j].z);
        tv[j].w = 0.5f * (tv[j].w + vb[j].w);
        const float dx = pv[j].x - tv[j].x, dy = pv[j].y - tv[j].y;
        const float dz = pv[j].z - tv[j].z, dw = pv[j].w - tv[j].w;
        lb[K0 + j][ti] = dx * dx + dy * dy + dz * dz + dw * dw;
        spP.x += __expf(pv[j].x); spP.y += __expf(pv[j].y);
        spP.z += __expf(pv[j].z); spP.w += __expf(pv[j].w);
        spT.x += __expf(tv[j].x); spT.y += __expf(tv[j].y);
        spT.z += __expf(tv[j].z); spT.w += __expf(tv[j].w);
    }
}

template<int K0, int NK>
__device__ __forceinline__ void score_write(float (*lb)[68], int ti,
                                            const float4* v, float4 inv) {
#pragma unroll
    for (int j = 0; j < NK; ++j) {
        const float m = fmaxf(fmaxf(__expf(v[j].x) * inv.x, __expf(v[j].y) * inv.y),
                              fmaxf(__expf(v[j].z) * inv.z, __expf(v[j].w) * inv.w));
        lb[K0 + j][ti] = m;
    }
}

// ---------------- K1: nt float4, 4-team split-k (R7/R9 best config) ------
__global__ __launch_bounds__(256, 4) void k1_reduce(const float* __restrict__ preds,
                                                    const float* __restrict__ targets,
                                                    float* __restrict__ ws) {
    __shared__ float lb[KJ][68];
    __shared__ float4 sP[4][64];
    __shared__ float4 sT[4][64];
    __shared__ float buf2[KJ][4];

    const int bid = blockIdx.x;
    const int b = bid >> 4;
    const int c = bid & 15;
    const int tid = threadIdx.x;
    const int tm = tid >> 6;
    const int ti = tid & 63;
    const int s0 = (c << 8) | (ti << 2);

    const float* pb  = preds   + (size_t)b * KJ * HW + s0;
    const float* t0b = targets + (size_t)b * KJ * HW + s0;
    const float* t1b = targets + (size_t)(BS + b) * KJ * HW + s0;

    float4 pv[5], tv[5], spP, spT;
    if      (tm == 0) team_pass1<0, 4>(pb, t0b, t1b, ti, lb, pv, tv, spP, spT);
    else if (tm == 1) team_pass1<4, 4>(pb, t0b, t1b, ti, lb, pv, tv, spP, spT);
    else if (tm == 2) team_pass1<8, 4>(pb, t0b, t1b, ti, lb, pv, tv, spP, spT);
    else              team_pass1<12, 5>(pb, t0b, t1b, ti, lb, pv, tv, spP, spT);
    sP[tm][ti] = spP;
    sT[tm][ti] = spT;
    __syncthreads();

    float4 invP, invT;
    {
        const float4 a0 = sP[0][ti], a1 = sP[1][ti], a2 = sP[2][ti], a3 = sP[3][ti];
        invP.x = 1.0f / (a0.x + a1.x + a2.x + a3.x);
        invP.y = 1.0f / (a0.y + a1.y + a2.y + a3.y);
        invP.z = 1.0f / (a0.z + a1.z + a2.z + a3.z);
        invP.w = 1.0f / (a0.w + a1.w + a2.w + a3.w);
        const float4 b0 = sT[0][ti], b1 = sT[1][ti], b2 = sT[2][ti], b3 = sT[3][ti];
        invT.x = 1.0f / (b0.x + b1.x + b2.x + b3.x);
        invT.y = 1.0f / (b0.y + b1.y + b2.y + b3.y);
        invT.z = 1.0f / (b0.z + b1.z + b2.z + b3.z);
        invT.w = 1.0f / (b0.w + b1.w + b2.w + b3.w);
    }

    if (tid < KJ * 4) {
        const int k = tid >> 2, seg = tid & 3;
        float r = 0.f;
#pragma unroll
        for (int i = 0; i < 16; ++i) {
            const int idx = (i + seg * 4) & 15;
            r += lb[k][(seg << 4) + idx];
        }
        buf2[k][seg] = r;
    }
    __syncthreads();

    if (tid < KJ) {
        ws[PL_OFF + bid * KJ + tid] =
            buf2[tid][0] + buf2[tid][1] + buf2[tid][2] + buf2[tid][3];
    }
    if      (tm == 0) score_write<0, 4>(lb, ti, pv, invP);
    else if (tm == 1) score_write<4, 4>(lb, ti, pv, invP);
    else if (tm == 2) score_write<8, 4>(lb, ti, pv, invP);
    else              score_write<12, 5>(lb, ti, pv, invP);
    __syncthreads();

    if (tid < KJ * 4) {
        const int k = tid >> 2, seg = tid & 3;
        float r = 0.f;
#pragma unroll
        for (int i = 0; i < 16; ++i) {
            const int idx = (i + seg * 4) & 15;
            r = fmaxf(r, lb[k][(seg << 4) + idx]);
        }
        buf2[k][seg] = r;
    }
    __syncthreads();

    if (tid < KJ) {
        ws[S1_OFF + bid * KJ + tid] = fmaxf(fmaxf(buf2[tid][0], buf2[tid][1]),
                                            fmaxf(buf2[tid][2], buf2[tid][3]));
    }
    if      (tm == 0) score_write<0, 4>(lb, ti, tv, invT);
    else if (tm == 1) score_write<4, 4>(lb, ti, tv, invT);
    else if (tm == 2) score_write<8, 4>(lb, ti, tv, invT);
    else              score_write<12, 5>(lb, ti, tv, invT);
    __syncthreads();

    if (tid < KJ * 4) {
        const int k = tid >> 2, seg = tid & 3;
        float r = 0.f;
#pragma unroll
        for (int i = 0; i < 16; ++i) {
            const int idx = (i + seg * 4) & 15;
            r = fmaxf(r, lb[k][(seg << 4) + idx]);
        }
        buf2[k][seg] = r;
    }
    __syncthreads();

    if (tid < KJ) {
        ws[S2_OFF + bid * KJ + tid] = fmaxf(fmaxf(buf2[tid][0], buf2[tid][1]),
                                            fmaxf(buf2[tid][2], buf2[tid][3]));
    }
}

// ---------------- K2: fold chunk partials ----------------
__global__ __launch_bounds__(256) void k2_fold(float* __restrict__ ws,
                                               const float* __restrict__ sw) {
    const int e = blockIdx.x * 256 + threadIdx.x;
    if (e >= NBK) return;
    const int b = e / KJ;
    const int k = e - b * KJ;
    float L = 0.f, S1 = 0.f, S2 = 0.f;
#pragma unroll
    for (int c = 0; c < CHUNKS; ++c) {
        const int idx = (b * CHUNKS + c) * KJ + k;
        L += ws[PL_OFF + idx];
        S1 = fmaxf(S1, ws[S1_OFF + idx]);
        S2 = fmaxf(S2, ws[S2_OFF + idx]);
    }
    ws[LW_OFF + e] = L * (1.0f / HW) * sw[b];
    ws[SA_OFF + e] = S1;
    ws[SB_OFF + e] = S2;
}

// ---------------- K3: order statistic (index KSEL of ascending sort) ----
__global__ __launch_bounds__(256) void k3_select(float* __restrict__ ws) {
    const int w = blockIdx.x * 4 + (threadIdx.x >> 6);  // 0..4351
    const int lane = threadIdx.x & 63;
    const int arr = (w >= NBK) ? 1 : 0;
    const int cand = w - arr * NBK;
    const float* sc = ws + (arr ? SB_OFF : SA_OFF);
    const float e = sc[cand];
    int clt = 0, cle = 0;
    for (int j = lane; j < NBK; j += 64) {
        float x = sc[j];
        clt += (x < e) ? 1 : 0;
        cle += (x <= e) ? 1 : 0;
    }
#pragma unroll
    for (int off = 32; off > 0; off >>= 1) {
        clt += __shfl_xor(clt, off, 64);
        cle += __shfl_xor(cle, off, 64);
    }
    if (lane == 0 && clt <= KSEL && KSEL < cle) {
        ws[THR_OFF + arr] = e;  // unique value; benign same-value race
    }
}

// ---------------- K4: finalize, fully parallel (512 thr) ----------------
__global__ __launch_bounds__(512) void k4_final(const float* __restrict__ ws,
                                                const float* __restrict__ sw,
                                                float* __restrict__ out) {
    const int tid = threadIdx.x;
    const int lane = tid & 63, wid = tid >> 6;
    const float thrA = ws[THR_OFF + 0];
    const float thrB = ws[THR_OFF + 1];

    float comb = 0.f, np = 0.f, ns = 0.f;
    for (int e = tid; e < NBK; e += 512) {
        const float L  = ws[LW_OFF + e];
        const float s1 = ws[SA_OFF + e];
        const float s2 = ws[SB_OFF + e];
        const float m = (s1 >= thrA && s2 >= thrB) ? 1.f : 0.f;
        comb += L * m;
        np += (L > 0.f) ? 1.f : 0.f;
        ns += m;
    }
#pragma unroll
    for (int off = 32; off > 0; off >>= 1) {
        comb += __shfl_xor(comb, off, 64);
        np   += __shfl_xor(np, off, 64);
        ns   += __shfl_xor(ns, off, 64);
    }
    __shared__ float wr[8][3];
    if (lane == 0) { wr[wid][0] = comb; wr[wid][1] = np; wr[wid][2] = ns; }
    __syncthreads();
    if (tid == 0) {
        float C = 0.f, NP = 0.f, NS = 0.f;
#pragma unroll
        for (int i = 0; i < 8; ++i) { C += wr[i][0]; NP += wr[i][1]; NS += wr[i][2]; }
        out[0] = C;
        out[1] = NP;
        out[2] = NS;
        out[20] = thrA;
        out[21] = thrB;
    }

    // joint_score_mean: 16 lanes per k, 8 b's per lane, 16-wide shfl reduce
    if (tid < KJ * 16) {
        const int k = tid >> 4, l = tid & 15;
        float a1 = 0.f, a2 = 0.f, cnt = 0.f;
#pragma unroll
        for (int i = 0; i < 8; ++i) {
            const int b = l + i * 16;
            const float wf = (sw[b] > 0.f) ? 1.f : 0.f;
            cnt += wf;
            a1 += ws[SA_OFF + b * KJ + k] * wf;
            a2 += ws[SB_OFF + b * KJ + k] * wf;
        }
#pragma unroll
        for (int off = 1; off < 16; off <<= 1) {
            a1  += __shfl_xor(a1, off, 16);
            a2  += __shfl_xor(a2, off, 16);
            cnt += __shfl_xor(cnt, off, 16);
        }
        if (l == 0) out[3 + k] = 0.5f * (a1 + a2) / cnt;
    }
}

extern "C" void kernel_launch(void* const* d_in, const int* in_sizes, int n_in,
                              void* d_out, int out_size, void* d_ws, size_t ws_size,
                              hipStream_t stream) {
    const float* preds   = (const float*)d_in[0];
    const float* targets = (const float*)d_in[1];
    const float* sw      = (const float*)d_in[2];
    float* out = (float*)d_out;
    float* ws  = (float*)d_ws;

    hipLaunchKernelGGL(k1_reduce, dim3(NBLK1), dim3(256), 0, stream, preds, targets, ws);
    hipLaunchKernelGGL(k2_fold, dim3((NBK + 255) / 256), dim3(256), 0, stream, ws, sw);
    hipLaunchKernelGGL(k3_select, dim3((2 * NBK) / 4), dim3(256), 0, stream, ws);
    hipLaunchKernelGGL(k4_final, dim3(1), dim3(512), 0, stream, ws, sw, out);
}